// Round 2
// baseline (3675.080 us; speedup 1.0000x reference)
//
#include <hip/hip_runtime.h>
#include <hip/hip_bf16.h>

// ---------------------------------------------------------------------------
// LocalizedPromptedAttentionLayer on MI355X (gfx950) — round 2: split design
// B=32, N=576 patches, W=16 kv-window, d=768, P=4 prompts, H=12 heads, Dh=64
//
//   q_x  = x @ (Wq@Wx)^T + (bq + Wq@bx)          [18432, 768] bf16 (ws)
//   qprm = prompt @ Wq^T + bq                     [4, 768] bf16
//   kv   = y @ [Wk@Wy ; Wv@Wy]^T + bias           [294912, 1536] bf16 (ws)
//   o    = softmax(q k^T / 8) v                   [92160, 768] bf16 (ws)
//   out  = o @ out_w^T + out_b                    [92160, 768] f32 -> d_out
// ---------------------------------------------------------------------------

typedef __attribute__((ext_vector_type(8))) short bf16x8;   // MFMA A/B frag
typedef __attribute__((ext_vector_type(4))) float f32x4;    // MFMA C/D frag
typedef __attribute__((ext_vector_type(4))) unsigned short u16x4;
typedef __attribute__((ext_vector_type(8))) unsigned short u16x8;

__device__ __forceinline__ float bf2f(unsigned short u) {
  union { unsigned int i; float f; } x; x.i = ((unsigned int)u) << 16; return x.f;
}
__device__ __forceinline__ unsigned short f2b(float f) {
  union { float f; unsigned int i; } x; x.f = f;
  unsigned int u = x.i;
  return (unsigned short)((u + 0x7fffu + ((u >> 16) & 1u)) >> 16);  // RNE
}

#define GLDS(gaddr, laddr) \
  __builtin_amdgcn_global_load_lds( \
      (const __attribute__((address_space(1))) unsigned int*)(gaddr), \
      (__attribute__((address_space(3))) unsigned int*)(laddr), 16, 0, 0)

// ---------------- f32 -> bf16 bulk convert ----------------
__global__ void k_f2b(const float* __restrict__ src, unsigned short* __restrict__ dst, int n4) {
  int stride = gridDim.x * blockDim.x;
  for (int i = blockIdx.x * blockDim.x + threadIdx.x; i < n4; i += stride) {
    float4 v = ((const float4*)src)[i];
    u16x4 o = { f2b(v.x), f2b(v.y), f2b(v.z), f2b(v.w) };
    ((u16x4*)dst)[i] = o;
  }
}

// ---------------- weight fusion: C[j,i] = sum_k A[j,k] * B[k,i] (bf16 out) ----------------
__global__ __launch_bounds__(256) void k_wfuse(const float* __restrict__ A,
                                               const float* __restrict__ Bm,
                                               unsigned short* __restrict__ C,
                                               int K, int lda, int ncols) {
  int i  = blockIdx.x * 256 + threadIdx.x;
  int j0 = blockIdx.y * 8;
  float acc[8] = {0.f,0.f,0.f,0.f,0.f,0.f,0.f,0.f};
  for (int k = 0; k < K; ++k) {
    float wb = Bm[(long)k * ncols + i];
#pragma unroll
    for (int r = 0; r < 8; ++r) acc[r] += A[(long)(j0 + r) * lda + k] * wb;
  }
#pragma unroll
  for (int r = 0; r < 8; ++r) C[(long)(j0 + r) * ncols + i] = f2b(acc[r]);
}

// ---------------- fused biases ----------------
__global__ void k_bfuse(const float* __restrict__ ipw, const float* __restrict__ ipb,
                        const float* __restrict__ bx, const float* __restrict__ by,
                        float* __restrict__ bqx, float* __restrict__ bkv) {
  int o    = blockIdx.x * 4 + (threadIdx.x >> 6);   // 0..2303 (grid 576)
  int lane = threadIdx.x & 63;
  int sec  = o / 768, jj = o - sec * 768;
  const float* Arow = ipw + (long)o * 768;
  const float* vb   = (sec == 0) ? bx : by;
  float s = 0.f;
  for (int k = lane; k < 768; k += 64) s += Arow[k] * vb[k];
#pragma unroll
  for (int d = 32; d > 0; d >>= 1) s += __shfl_down(s, d);
  if (lane == 0) {
    s += ipb[o];
    if (sec == 0) bqx[jj] = s;
    else if (sec == 1) bkv[jj] = s;
    else bkv[768 + jj] = s;
  }
}

// ---------------- prompt queries ----------------
__global__ void k_qprompt(const float* __restrict__ ipw, const float* __restrict__ ipb,
                          const float* __restrict__ prompt, unsigned short* __restrict__ qpf) {
  int o    = blockIdx.x * 4 + (threadIdx.x >> 6);   // 0..3071 (grid 768)
  int lane = threadIdx.x & 63;
  int p = o / 768, j = o - p * 768;
  const float* Wqr = ipw + (long)j * 768;
  const float* pr  = prompt + (long)p * 768;
  float s = 0.f;
  for (int k = lane; k < 768; k += 64) s += Wqr[k] * pr[k];
#pragma unroll
  for (int d = 32; d > 0; d >>= 1) s += __shfl_down(s, d);
  if (lane == 0) qpf[o] = f2b(s + ipb[j]);
}

// ---------------- GEMM: C[M,N] = A[M,K] @ Bw_bf16[N,K]^T + bias ----------------
// 128x128 tile, BK=32, 256 thr (4 waves 2x2), double-buffered LDS.
// B staged via global_load_lds (16B). A: AF32 ? f32 reg-stage+cvt : global_load_lds.
// Grid linear, XCD-bijective swizzle, N-tile fastest (A-panel L2 reuse per XCD).
template <bool AF32, typename OutT>
__global__ __launch_bounds__(256) void k_gemm(const void* __restrict__ Ap,
                                              const unsigned short* __restrict__ Bw,
                                              const float* __restrict__ bias,
                                              OutT* __restrict__ C,
                                              int M, int Nn, int K, int nbx) {
  const int tid  = threadIdx.x;
  const int lane = tid & 63, wid = tid >> 6;
  const int wm = wid >> 1, wn = wid & 1;
  const int lr = lane & 15, lk = lane >> 4;

  // XCD-bijective swizzle (m204): hardware round-robins orig%8 -> XCD;
  // remap so each XCD owns a contiguous wg range; nt fastest => A-panel reuse.
  const int nwg = gridDim.x, orig = blockIdx.x;
  const int q8 = nwg >> 3, r8 = nwg & 7, xc = orig & 7;
  const int wg = (xc < r8 ? xc * (q8 + 1) : r8 * (q8 + 1) + (xc - r8) * q8) + (orig >> 3);
  const int bn = wg % nbx, bm = wg / nbx;
  const int m0 = bm * 128, n0 = bn * 128;

  __shared__ unsigned short As[2][128 * 32];
  __shared__ unsigned short Bs[2][128 * 32];

  const float*          Af = (const float*)Ap;
  const unsigned short* Ab = (const unsigned short*)Ap;

  f32x4 acc[4][4];
#pragma unroll
  for (int nt = 0; nt < 4; ++nt) {
    float bv = bias[n0 + wn * 64 + nt * 16 + lr];
    f32x4 bvv = {bv, bv, bv, bv};
#pragma unroll
    for (int mt = 0; mt < 4; ++mt) acc[mt][nt] = bvv;
  }

  const int NS = K >> 5;
  const int crow = (lane >> 2), ck8 = (lane & 3) * 8;  // within-chunk mapping (lane*16B)

  auto stageB = [&](int buf, int ks) {
#pragma unroll
    for (int i = 0; i < 2; ++i) {
      int c = wid * 2 + i;                       // chunk 0..7, wave-uniform base
      int row = c * 16 + crow;
      GLDS(&Bw[(long)(n0 + row) * K + ks * 32 + ck8], &Bs[buf][c * 512]);
    }
  };
  auto stageA_lds = [&](int buf, int ks) {
#pragma unroll
    for (int i = 0; i < 2; ++i) {
      int c = wid * 2 + i;
      int row = c * 16 + crow;
      GLDS(&Ab[(long)(m0 + row) * K + ks * 32 + ck8], &As[buf][c * 512]);
    }
  };
  float4 ra[2][2];
  auto ldA = [&](int ks) {
#pragma unroll
    for (int s = 0; s < 2; ++s) {
      int c = tid + s * 256, row = c >> 2, k8 = (c & 3) * 8;
      const float* src = &Af[(long)(m0 + row) * K + ks * 32 + k8];
      ra[s][0] = *(const float4*)src;
      ra[s][1] = *(const float4*)(src + 4);
    }
  };
  auto stA = [&](int buf) {
#pragma unroll
    for (int s = 0; s < 2; ++s) {
      int c = tid + s * 256, row = c >> 2, k8 = (c & 3) * 8;
      float4 v0 = ra[s][0], v1 = ra[s][1];
      u16x8 t = { f2b(v0.x), f2b(v0.y), f2b(v0.z), f2b(v0.w),
                  f2b(v1.x), f2b(v1.y), f2b(v1.z), f2b(v1.w) };
      *(u16x8*)&As[buf][row * 32 + k8] = t;
    }
  };

  // prologue: fill buf0
  stageB(0, 0);
  if constexpr (AF32) { ldA(0); stA(0); }
  else                stageA_lds(0, 0);
  __syncthreads();

  for (int t = 0; t < NS; ++t) {
    const int cur = t & 1, nb = cur ^ 1;
    if (t + 1 < NS) {
      stageB(nb, t + 1);
      if constexpr (AF32) ldA(t + 1);
      else                stageA_lds(nb, t + 1);
    }
    bf16x8 af[4], bfr[4];
#pragma unroll
    for (int mt = 0; mt < 4; ++mt)
      af[mt] = *(const bf16x8*)&As[cur][(wm * 64 + mt * 16 + lr) * 32 + lk * 8];
#pragma unroll
    for (int nt = 0; nt < 4; ++nt)
      bfr[nt] = *(const bf16x8*)&Bs[cur][(wn * 64 + nt * 16 + lr) * 32 + lk * 8];
#pragma unroll
    for (int mt = 0; mt < 4; ++mt)
#pragma unroll
      for (int nt = 0; nt < 4; ++nt)
        acc[mt][nt] = __builtin_amdgcn_mfma_f32_16x16x32_bf16(af[mt], bfr[nt], acc[mt][nt], 0, 0, 0);
    if constexpr (AF32) { if (t + 1 < NS) stA(nb); }
    __syncthreads();
  }

#pragma unroll
  for (int mt = 0; mt < 4; ++mt)
#pragma unroll
    for (int nt = 0; nt < 4; ++nt) {
      int col = n0 + wn * 64 + nt * 16 + lr;
#pragma unroll
      for (int r = 0; r < 4; ++r) {
        int row = m0 + wm * 64 + mt * 16 + lk * 4 + r;
        float v = acc[mt][nt][r];
        if constexpr (sizeof(OutT) == 4) C[(long)row * Nn + col] = v;
        else                             C[(long)row * Nn + col] = f2b(v);
      }
    }
}

// ---------------- streaming attention ----------------
// 1 block = 8 patches, 512 threads. kv rows [patch*16 .. +16) hold [k|v] (1536).
// scores+softmax: 7680 items, 16-lane w-groups reduce via shfl_xor. PV: coalesced v.
__global__ __launch_bounds__(512) void k_attn(const unsigned short* __restrict__ kv,
                                              const unsigned short* __restrict__ qx,
                                              const unsigned short* __restrict__ qp,
                                              unsigned short* __restrict__ o) {
  __shared__ unsigned short Qs[12][768];   // rows 0..7: qx of 8 patches; 8..11: prompts
  __shared__ float Ss[480][16];            // attn[(p*5+q5)*12+h][w]
  const int tid = threadIdx.x;
  const long p0 = (long)blockIdx.x * 8;

  for (int i = tid; i < 12 * 96; i += 512) {
    int r = i / 96, c = i - r * 96;
    const unsigned short* src = (r < 8) ? &qx[(p0 + r) * 768 + c * 8]
                                        : &qp[(long)(r - 8) * 768 + c * 8];
    *(u16x8*)&Qs[r][c * 8] = *(const u16x8*)src;
  }
  __syncthreads();

  // scores + in-wave softmax (16-lane groups = one (p,q5,h) row over w)
#pragma unroll 1
  for (int it = 0; it < 15; ++it) {
    int idx = tid + it * 512;
    int w = idx & 15, rest = idx >> 4;        // rest 0..479
    int h = rest % 12, pq = rest / 12;
    int q5 = pq % 5, p = pq / 5;
    const u16x8* krow = (const u16x8*)&kv[((p0 + p) * 16 + w) * 1536 + h * 64];
    const u16x8* qrow = (const u16x8*)((q5 == 0) ? &Qs[p][h * 64] : &Qs[7 + q5][h * 64]);
    float s = 0.f;
#pragma unroll
    for (int j = 0; j < 8; ++j) {
      u16x8 kk = krow[j], qq = qrow[j];
#pragma unroll
      for (int e = 0; e < 8; ++e) s += bf2f(qq[e]) * bf2f(kk[e]);
    }
    s *= 0.125f;
    float m = s;
#pragma unroll
    for (int d = 1; d < 16; d <<= 1) m = fmaxf(m, __shfl_xor(m, d));
    float e = __expf(s - m);
    float sum = e;
#pragma unroll
    for (int d = 1; d < 16; d <<= 1) sum += __shfl_xor(sum, d);
    Ss[rest][w] = e / sum;
  }
  __syncthreads();

  // PV: 30720 outputs; per-wave d is consecutive -> coalesced v loads, Ss broadcast
#pragma unroll 1
  for (int it = 0; it < 60; ++it) {
    int idx = tid + it * 512;
    int d = idx % 768, pq = idx / 768;
    int q5 = pq % 5, p = pq / 5;
    int h = d >> 6;
    const float* arow = Ss[(pq)*12 + h - (q5 ? 0 : 0)];  // row (p*5+q5)*12+h == pq*12+h
    const unsigned short* vcol = &kv[(p0 + p) * 16 * 1536 + 768 + d];
    float acc = 0.f;
#pragma unroll
    for (int w = 0; w < 16; ++w) acc += arow[w] * bf2f(vcol[(long)w * 1536]);
    o[((p0 + p) * 5 + q5) * 768 + d] = f2b(acc);
  }
}

// ---------------------------------------------------------------------------
extern "C" void kernel_launch(void* const* d_in, const int* in_sizes, int n_in,
                              void* d_out, int out_size, void* d_ws, size_t ws_size,
                              hipStream_t stream) {
  const float* x      = (const float*)d_in[0];   // [32,576,1536]
  const float* y      = (const float*)d_in[1];   // [32,9216,1024]
  const float* Wx     = (const float*)d_in[2];   // [768,1536]
  const float* bx     = (const float*)d_in[3];   // [768]
  const float* Wy     = (const float*)d_in[4];   // [768,1024]
  const float* by     = (const float*)d_in[5];   // [768]
  const float* prompt = (const float*)d_in[6];   // [1,4,768]
  const float* ipw    = (const float*)d_in[7];   // [2304,768]
  const float* ipb    = (const float*)d_in[8];   // [2304]
  const float* outw   = (const float*)d_in[9];   // [768,768]
  const float* outb   = (const float*)d_in[10];  // [768]
  float* out = (float*)d_out;

  char* ws = (char*)d_ws;
  size_t off = 0;
  auto alloc = [&](size_t bytes) -> void* {
    void* p = ws + off; off += (bytes + 255) & ~(size_t)255; return p;
  };
  unsigned short* kvb  = (unsigned short*)alloc(294912UL * 1536 * 2);  // 906 MB
  unsigned short* qxb  = (unsigned short*)alloc(18432UL * 768 * 2);    // 28 MB
  unsigned short* ob   = (unsigned short*)alloc(92160UL * 768 * 2);    // 142 MB
  unsigned short* Wqx  = (unsigned short*)alloc(768UL * 1536 * 2);
  unsigned short* Wkv  = (unsigned short*)alloc(1536UL * 1024 * 2);
  unsigned short* oww  = (unsigned short*)alloc(768UL * 768 * 2);
  unsigned short* qpf  = (unsigned short*)alloc(4UL * 768 * 2);
  float*          bqx  = (float*)alloc(768 * 4);
  float*          bkv  = (float*)alloc(1536 * 4);

  // ---- weight prep ----
  k_f2b<<<dim3(256), dim3(256), 0, stream>>>(outw, oww, 768 * 768 / 4);
  k_wfuse<<<dim3(6, 96), dim3(256), 0, stream>>>(ipw,              Wx, Wqx,              768, 768, 1536);
  k_wfuse<<<dim3(4, 96), dim3(256), 0, stream>>>(ipw + 768 * 768,  Wy, Wkv,              768, 768, 1024);
  k_wfuse<<<dim3(4, 96), dim3(256), 0, stream>>>(ipw + 1536 * 768, Wy, Wkv + 768 * 1024, 768, 768, 1024);
  k_bfuse<<<dim3(576), dim3(256), 0, stream>>>(ipw, ipb, bx, by, bqx, bkv);
  k_qprompt<<<dim3(768), dim3(256), 0, stream>>>(ipw, ipb, prompt, qpf);

  // ---- q_x = x @ Wqx^T + bqx  (M=18432, N=768, K=1536) -> bf16 ----
  k_gemm<true, unsigned short><<<dim3(144 * 6), dim3(256), 0, stream>>>(
      (const void*)x, Wqx, bqx, qxb, 18432, 768, 1536, 6);

  // ---- kv = y @ Wkv^T + bkv  (M=294912, N=1536, K=1024) -> bf16 ----
  k_gemm<true, unsigned short><<<dim3(2304 * 12), dim3(256), 0, stream>>>(
      (const void*)y, Wkv, bkv, kvb, 294912, 1536, 1024, 12);

  // ---- attention -> o bf16 ----
  k_attn<<<dim3(2304), dim3(512), 0, stream>>>(kvb, qxb, qpf, ob);

  // ---- out = o @ oww^T + outb  (M=92160, N=768, K=768) -> f32 ----
  k_gemm<false, float><<<dim3(720 * 6), dim3(256), 0, stream>>>(
      (const void*)ob, oww, outb, out, 92160, 768, 768, 6);
}

// Round 3
// 3065.328 us; speedup vs baseline: 1.1989x; 1.1989x over previous
//
#include <hip/hip_runtime.h>
#include <hip/hip_bf16.h>

// ---------------------------------------------------------------------------
// LocalizedPromptedAttentionLayer on MI355X (gfx950) — round 3
// B=32, N=576 patches, W=16 kv-window, d=768, P=4 prompts, H=12 heads, Dh=64
//
//   xb   = bf16(x)                                [18432, 1536]  (aliased in ob)
//   q_x  = xb @ (Wq@Wx)^T + (bq + Wq@bx)          [18432, 768] bf16
//   qprm = prompt @ Wq^T + bq                     [4, 768] bf16
//   yb   = bf16(y)  (chunked vs ws_size)          [rows, 1024]
//   kv   = yb @ [Wk@Wy ; Wv@Wy]^T + bias          [294912, 1536] bf16
//   o    = softmax(q k^T / 8) v                   [92160, 768] bf16
//   out  = o @ out_w^T + out_b                    [92160, 768] f32 -> d_out
// ---------------------------------------------------------------------------

typedef __attribute__((ext_vector_type(8))) short bf16x8;   // MFMA A/B frag
typedef __attribute__((ext_vector_type(4))) float f32x4;    // MFMA C/D frag
typedef __attribute__((ext_vector_type(8))) unsigned short u16x8;

__device__ __forceinline__ float bf2f(unsigned short u) {
  union { unsigned int i; float f; } x; x.i = ((unsigned int)u) << 16; return x.f;
}
__device__ __forceinline__ unsigned short f2b(float f) {
  union { float f; unsigned int i; } x; x.f = f;
  unsigned int u = x.i;
  return (unsigned short)((u + 0x7fffu + ((u >> 16) & 1u)) >> 16);  // RNE
}

#define GLDS(gaddr, laddr) \
  __builtin_amdgcn_global_load_lds( \
      (const __attribute__((address_space(1))) unsigned int*)(gaddr), \
      (__attribute__((address_space(3))) unsigned int*)(laddr), 16, 0, 0)

// ---------------- f32 -> bf16 bulk convert (8 elems/thread-iter) ----------------
__global__ void k_cvt(const float* __restrict__ src, unsigned short* __restrict__ dst, long n8) {
  long stride = (long)gridDim.x * blockDim.x;
  for (long i = (long)blockIdx.x * blockDim.x + threadIdx.x; i < n8; i += stride) {
    float4 a = ((const float4*)src)[2 * i];
    float4 b = ((const float4*)src)[2 * i + 1];
    u16x8 t = { f2b(a.x), f2b(a.y), f2b(a.z), f2b(a.w),
                f2b(b.x), f2b(b.y), f2b(b.z), f2b(b.w) };
    ((u16x8*)dst)[i] = t;
  }
}

// ---------------- weight fusion: C[j,i] = sum_k A[j,k] * B[k,i] (bf16 out) ----------------
__global__ __launch_bounds__(256) void k_wfuse(const float* __restrict__ A,
                                               const float* __restrict__ Bm,
                                               unsigned short* __restrict__ C,
                                               int K, int lda, int ncols) {
  int i  = blockIdx.x * 256 + threadIdx.x;
  int j0 = blockIdx.y * 8;
  float acc[8] = {0.f,0.f,0.f,0.f,0.f,0.f,0.f,0.f};
  for (int k = 0; k < K; ++k) {
    float wb = Bm[(long)k * ncols + i];
#pragma unroll
    for (int r = 0; r < 8; ++r) acc[r] += A[(long)(j0 + r) * lda + k] * wb;
  }
#pragma unroll
  for (int r = 0; r < 8; ++r) C[(long)(j0 + r) * ncols + i] = f2b(acc[r]);
}

// ---------------- fused biases ----------------
__global__ void k_bfuse(const float* __restrict__ ipw, const float* __restrict__ ipb,
                        const float* __restrict__ bx, const float* __restrict__ by,
                        float* __restrict__ bqx, float* __restrict__ bkv) {
  int o    = blockIdx.x * 4 + (threadIdx.x >> 6);   // 0..2303 (grid 576)
  int lane = threadIdx.x & 63;
  int sec  = o / 768, jj = o - sec * 768;
  const float* Arow = ipw + (long)o * 768;
  const float* vb   = (sec == 0) ? bx : by;
  float s = 0.f;
  for (int k = lane; k < 768; k += 64) s += Arow[k] * vb[k];
#pragma unroll
  for (int d = 32; d > 0; d >>= 1) s += __shfl_down(s, d);
  if (lane == 0) {
    s += ipb[o];
    if (sec == 0) bqx[jj] = s;
    else if (sec == 1) bkv[jj] = s;
    else bkv[768 + jj] = s;
  }
}

// ---------------- prompt queries ----------------
__global__ void k_qprompt(const float* __restrict__ ipw, const float* __restrict__ ipb,
                          const float* __restrict__ prompt, unsigned short* __restrict__ qpf) {
  int o    = blockIdx.x * 4 + (threadIdx.x >> 6);   // 0..3071 (grid 768)
  int lane = threadIdx.x & 63;
  int p = o / 768, j = o - p * 768;
  const float* Wqr = ipw + (long)j * 768;
  const float* pr  = prompt + (long)p * 768;
  float s = 0.f;
  for (int k = lane; k < 768; k += 64) s += Wqr[k] * pr[k];
#pragma unroll
  for (int d = 32; d > 0; d >>= 1) s += __shfl_down(s, d);
  if (lane == 0) qpf[o] = f2b(s + ipb[j]);
}

// ---------------- GEMM: C[M,N] = A_bf16[M,K] @ Bw_bf16[N,K]^T + bias ----------------
// 128x128 tile, BK=32, 256 thr (4 waves 2x2), double-buffered LDS,
// global_load_lds (16B) on BOTH operands (m97 structure), XCD-bijective swizzle.
template <typename OutT>
__global__ __launch_bounds__(256) void k_gemm(const unsigned short* __restrict__ A,
                                              const unsigned short* __restrict__ Bw,
                                              const float* __restrict__ bias,
                                              OutT* __restrict__ C,
                                              int M, int Nn, int K, int nbx) {
  const int tid  = threadIdx.x;
  const int lane = tid & 63, wid = tid >> 6;
  const int wm = wid >> 1, wn = wid & 1;
  const int lr = lane & 15, lk = lane >> 4;

  // XCD-bijective swizzle (m204); nt fastest => A-panel reuse within an XCD.
  const int nwg = gridDim.x, orig = blockIdx.x;
  const int q8 = nwg >> 3, r8 = nwg & 7, xc = orig & 7;
  const int wg = (xc < r8 ? xc * (q8 + 1) : r8 * (q8 + 1) + (xc - r8) * q8) + (orig >> 3);
  const int bn = wg % nbx, bm = wg / nbx;
  const int m0 = bm * 128, n0 = bn * 128;

  __shared__ unsigned short As[2][128 * 32];
  __shared__ unsigned short Bs[2][128 * 32];

  f32x4 acc[4][4];
#pragma unroll
  for (int nt = 0; nt < 4; ++nt) {
    float bv = bias[n0 + wn * 64 + nt * 16 + lr];
    f32x4 bvv = {bv, bv, bv, bv};
#pragma unroll
    for (int mt = 0; mt < 4; ++mt) acc[mt][nt] = bvv;
  }

  const int NS = K >> 5;
  const int crow = lane >> 2, ck8 = (lane & 3) * 8;  // within 1KB chunk: lane*16B

  auto stage = [&](int buf, int ks) {
#pragma unroll
    for (int i = 0; i < 2; ++i) {
      int c = wid * 2 + i;                       // chunk 0..7 (16 rows each)
      int row = c * 16 + crow;
      GLDS(&A[(long)(m0 + row) * K + ks * 32 + ck8], &As[buf][c * 512]);
      GLDS(&Bw[(long)(n0 + row) * K + ks * 32 + ck8], &Bs[buf][c * 512]);
    }
  };

  stage(0, 0);
  __syncthreads();

  for (int t = 0; t < NS; ++t) {
    const int cur = t & 1, nb = cur ^ 1;
    if (t + 1 < NS) stage(nb, t + 1);
    bf16x8 af[4], bfr[4];
#pragma unroll
    for (int mt = 0; mt < 4; ++mt)
      af[mt] = *(const bf16x8*)&As[cur][(wm * 64 + mt * 16 + lr) * 32 + lk * 8];
#pragma unroll
    for (int nt = 0; nt < 4; ++nt)
      bfr[nt] = *(const bf16x8*)&Bs[cur][(wn * 64 + nt * 16 + lr) * 32 + lk * 8];
#pragma unroll
    for (int mt = 0; mt < 4; ++mt)
#pragma unroll
      for (int nt = 0; nt < 4; ++nt)
        acc[mt][nt] = __builtin_amdgcn_mfma_f32_16x16x32_bf16(af[mt], bfr[nt], acc[mt][nt], 0, 0, 0);
    __syncthreads();
  }

#pragma unroll
  for (int mt = 0; mt < 4; ++mt)
#pragma unroll
    for (int nt = 0; nt < 4; ++nt) {
      int col = n0 + wn * 64 + nt * 16 + lr;
#pragma unroll
      for (int r = 0; r < 4; ++r) {
        int row = m0 + wm * 64 + mt * 16 + lk * 4 + r;
        float v = acc[mt][nt][r];
        if constexpr (sizeof(OutT) == 4) C[(long)row * Nn + col] = v;
        else                             C[(long)row * Nn + col] = f2b(v);
      }
    }
}

// ---------------- attention, coalesced ----------------
// 1 block = 2 patches, 512 threads, ~66 KB LDS (2 blocks/CU).
// K staged to LDS (contiguous u16x8 copies, padded stride 772).
// Scores: 16-lane groups, K from LDS, shfl softmax. PV: 8 outputs/lane,
// v loads 16 B/lane contiguous (d-fast), o written u16x8.
__global__ __launch_bounds__(512) void k_attn(const unsigned short* __restrict__ kv,
                                              const unsigned short* __restrict__ qx,
                                              const unsigned short* __restrict__ qp,
                                              unsigned short* __restrict__ o) {
  __shared__ unsigned short Ks[32 * 772];   // 2 patches x 16 w, padded row stride
  __shared__ unsigned short Qs[6 * 768];    // 2 x-rows + 4 prompts
  __shared__ float Ss[120 * 16];            // (pq*12+h) x w
  const int tid = threadIdx.x;
  const long p0 = (long)blockIdx.x * 2;

  // stage K (coalesced: 1.5KB contiguous per kv row)
  for (int i = tid; i < 32 * 96; i += 512) {
    int r = i / 96, c8 = i - (i / 96) * 96;
    u16x8 vv = *(const u16x8*)&kv[((p0 + (r >> 4)) * 16 + (r & 15)) * 1536 + c8 * 8];
    *(u16x8*)&Ks[r * 772 + c8 * 8] = vv;
  }
  // stage Q
  for (int i = tid; i < 6 * 96; i += 512) {
    int r = i / 96, c8 = i - (i / 96) * 96;
    const unsigned short* src = (r < 2) ? &qx[(p0 + r) * 768 + c8 * 8]
                                        : &qp[(long)(r - 2) * 768 + c8 * 8];
    *(u16x8*)&Qs[r * 768 + c8 * 8] = *(const u16x8*)src;
  }
  __syncthreads();

  // scores + softmax: 2p x 5q x 12h x 16w = 1920 items
  for (int idx = tid; idx < 1920; idx += 512) {
    int w = idx & 15, rest = idx >> 4;       // rest = pq*12 + h
    int h = rest % 12, pq = rest / 12;
    int q5 = pq % 5, p = pq / 5;
    const unsigned short* krow = &Ks[(p * 16 + w) * 772 + h * 64];
    const unsigned short* qrow = &Qs[((q5 == 0) ? p : 1 + q5) * 768 + h * 64];
    float s = 0.f;
#pragma unroll
    for (int j = 0; j < 8; ++j) {
      u16x8 kk = *(const u16x8*)&krow[j * 8];
      u16x8 qq = *(const u16x8*)&qrow[j * 8];
#pragma unroll
      for (int e = 0; e < 8; ++e) s += bf2f(qq[e]) * bf2f(kk[e]);
    }
    s *= 0.125f;
    float m = s;
#pragma unroll
    for (int d = 1; d < 16; d <<= 1) m = fmaxf(m, __shfl_xor(m, d));
    float e = __expf(s - m);
    float sum = e;
#pragma unroll
    for (int d = 1; d < 16; d <<= 1) sum += __shfl_xor(sum, d);
    Ss[rest * 16 + w] = e / sum;
  }
  __syncthreads();

  // PV: 10 pq-rows x 96 d8-chunks; 8 outputs per lane; v 16B/lane coalesced
  for (int idx = tid; idx < 960; idx += 512) {
    int d8 = idx % 96, pq = idx / 96;
    int q5 = pq % 5, p = pq / 5, h = d8 >> 3;
    const float* arow = &Ss[(pq * 12 + h) * 16];
    const unsigned short* vbase = &kv[(p0 + p) * 16 * 1536 + 768 + d8 * 8];
    float acc[8] = {0.f,0.f,0.f,0.f,0.f,0.f,0.f,0.f};
#pragma unroll
    for (int w = 0; w < 16; ++w) {
      u16x8 vv = *(const u16x8*)&vbase[(long)w * 1536];
      float aw = arow[w];
#pragma unroll
      for (int e = 0; e < 8; ++e) acc[e] += aw * bf2f(vv[e]);
    }
    u16x8 ov;
#pragma unroll
    for (int e = 0; e < 8; ++e) ov[e] = f2b(acc[e]);
    *(u16x8*)&o[((p0 + p) * 5 + q5) * 768 + d8 * 8] = ov;
  }
}

// ---------------------------------------------------------------------------
extern "C" void kernel_launch(void* const* d_in, const int* in_sizes, int n_in,
                              void* d_out, int out_size, void* d_ws, size_t ws_size,
                              hipStream_t stream) {
  const float* x      = (const float*)d_in[0];   // [32,576,1536]
  const float* y      = (const float*)d_in[1];   // [32,9216,1024]
  const float* bx     = (const float*)d_in[3];   // [768]
  const float* Wx     = (const float*)d_in[2];   // [768,1536]
  const float* Wy     = (const float*)d_in[4];   // [768,1024]
  const float* by     = (const float*)d_in[5];   // [768]
  const float* prompt = (const float*)d_in[6];   // [1,4,768]
  const float* ipw    = (const float*)d_in[7];   // [2304,768]
  const float* ipb    = (const float*)d_in[8];   // [2304]
  const float* outw   = (const float*)d_in[9];   // [768,768]
  const float* outb   = (const float*)d_in[10];  // [768]
  float* out = (float*)d_out;

  char* ws = (char*)d_ws;
  size_t off = 0;
  auto alloc = [&](size_t bytes) -> void* {
    void* p = ws + off; off += (bytes + 255) & ~(size_t)255; return p;
  };
  unsigned short* kvb  = (unsigned short*)alloc(294912UL * 1536 * 2);  // 906 MB
  unsigned short* qxb  = (unsigned short*)alloc(18432UL * 768 * 2);    // 28 MB
  unsigned short* ob   = (unsigned short*)alloc(92160UL * 768 * 2);    // 142 MB
  unsigned short* Wqx  = (unsigned short*)alloc(768UL * 1536 * 2);
  unsigned short* Wkv  = (unsigned short*)alloc(1536UL * 1024 * 2);
  unsigned short* oww  = (unsigned short*)alloc(768UL * 768 * 2);
  unsigned short* qpf  = (unsigned short*)alloc(4UL * 768 * 2);
  float*          bqx  = (float*)alloc(768 * 4);
  float*          bkv  = (float*)alloc(1536 * 4);
  // xb aliases ob (56.6 MB <= 141.6 MB; dead before k_attn writes ob)
  unsigned short* xb   = ob;
  // y bf16 chunk buffer: whatever workspace remains
  unsigned short* ybc  = (unsigned short*)(ws + off);
  long rpc = (long)((ws_size - off) / (1024 * 2)) & ~127L;  // rows per chunk (mult of 128)
  if (rpc > 294912) rpc = 294912;
  if (rpc < 128) rpc = 128;

  // ---- weight prep ----
  k_cvt<<<dim3(288), dim3(256), 0, stream>>>(outw, oww, 768L * 768 / 8);
  k_wfuse<<<dim3(6, 96), dim3(256), 0, stream>>>(ipw,              Wx, Wqx,              768, 768, 1536);
  k_wfuse<<<dim3(4, 96), dim3(256), 0, stream>>>(ipw + 768 * 768,  Wy, Wkv,              768, 768, 1024);
  k_wfuse<<<dim3(4, 96), dim3(256), 0, stream>>>(ipw + 1536 * 768, Wy, Wkv + 768 * 1024, 768, 768, 1024);
  k_bfuse<<<dim3(576), dim3(256), 0, stream>>>(ipw, ipb, bx, by, bqx, bkv);
  k_qprompt<<<dim3(768), dim3(256), 0, stream>>>(ipw, ipb, prompt, qpf);

  // ---- x -> bf16; q_x = xb @ Wqx^T + bqx  (M=18432, N=768, K=1536) ----
  k_cvt<<<dim3(2048), dim3(256), 0, stream>>>(x, xb, 18432L * 1536 / 8);
  k_gemm<unsigned short><<<dim3(144 * 6), dim3(256), 0, stream>>>(
      xb, Wqx, bqx, qxb, 18432, 768, 1536, 6);

  // ---- kv = bf16(y) @ Wkv^T + bkv  (M=294912, N=1536, K=1024), chunked ----
  long row0 = 0;
  while (row0 < 294912) {
    long mc = 294912 - row0 < rpc ? 294912 - row0 : rpc;
    k_cvt<<<dim3(2048), dim3(256), 0, stream>>>(y + row0 * 1024, ybc, mc * 128);
    k_gemm<unsigned short><<<dim3((int)(mc / 128) * 12), dim3(256), 0, stream>>>(
        ybc, Wkv, bkv, kvb + row0 * 1536, (int)mc, 1536, 1024, 12);
    row0 += mc;
  }

  // ---- attention -> o bf16 ----
  k_attn<<<dim3(9216), dim3(512), 0, stream>>>(kvb, qxb, qpf, ob);

  // ---- out = o @ oww^T + outb  (M=92160, N=768, K=768) -> f32 ----
  k_gemm<float><<<dim3(720 * 6), dim3(256), 0, stream>>>(
      ob, oww, outb, out, 92160, 768, 768, 6);
}

// Round 5
// 2831.495 us; speedup vs baseline: 1.2979x; 1.0826x over previous
//
#include <hip/hip_runtime.h>
#include <hip/hip_bf16.h>

// ---------------------------------------------------------------------------
// LocalizedPromptedAttentionLayer on MI355X (gfx950) — round 5
// B=32, N=576 patches, W=16 kv-window, d=768, P=4 prompts, H=12 heads, Dh=64
//
//   xb   = bf16(x)                                [18432, 1536]  (aliased in ob)
//   q_x  = xb @ (Wq@Wx)^T + (bq + Wq@bx)          [18432, 768] bf16   (128² GEMM)
//   qprm = prompt @ Wq^T + bq                     [4, 768] bf16
//   yb   = bf16(y)  (chunked vs ws_size)          [rows, 1024]
//   kv   = yb @ [Wk@Wy ; Wv@Wy]^T + bias          [294912, 1536] bf16 (256² 8-phase)
//   o    = softmax(q k^T / 8) v                   [92160, 768] bf16
//   out  = o @ out_w^T + out_b                    [92160, 768] f32    (256² 8-phase)
//
// Round-5 fix vs round 4: counted vmcnt drain moved BEFORE the iteration's
// closing s_barrier (was after), so the barrier publishes all waves' landed
// global_load_lds data before anyone ds_reads the next tile. (Cross-wave
// LDS visibility race -> rare small corruption -> absmax 6.3e-3.)
// ---------------------------------------------------------------------------

typedef __attribute__((ext_vector_type(8))) short bf16x8;   // MFMA A/B frag
typedef __attribute__((ext_vector_type(4))) float f32x4;    // MFMA C/D frag
typedef __attribute__((ext_vector_type(8))) unsigned short u16x8;

__device__ __forceinline__ float bf2f(unsigned short u) {
  union { unsigned int i; float f; } x; x.i = ((unsigned int)u) << 16; return x.f;
}
__device__ __forceinline__ unsigned short f2b(float f) {
  union { float f; unsigned int i; } x; x.f = f;
  unsigned int u = x.i;
  return (unsigned short)((u + 0x7fffu + ((u >> 16) & 1u)) >> 16);  // RNE
}

#define GLDS(gaddr, laddr) \
  __builtin_amdgcn_global_load_lds( \
      (const __attribute__((address_space(1))) unsigned int*)(gaddr), \
      (__attribute__((address_space(3))) unsigned int*)(laddr), 16, 0, 0)

// ---------------- f32 -> bf16 bulk convert (8 elems/thread-iter) ----------------
__global__ void k_cvt(const float* __restrict__ src, unsigned short* __restrict__ dst, long n8) {
  long stride = (long)gridDim.x * blockDim.x;
  for (long i = (long)blockIdx.x * blockDim.x + threadIdx.x; i < n8; i += stride) {
    float4 a = ((const float4*)src)[2 * i];
    float4 b = ((const float4*)src)[2 * i + 1];
    u16x8 t = { f2b(a.x), f2b(a.y), f2b(a.z), f2b(a.w),
                f2b(b.x), f2b(b.y), f2b(b.z), f2b(b.w) };
    ((u16x8*)dst)[i] = t;
  }
}

// ---------------- weight fusion: C[j,i] = sum_k A[j,k] * B[k,i] (bf16 out) ----------------
__global__ __launch_bounds__(256) void k_wfuse(const float* __restrict__ A,
                                               const float* __restrict__ Bm,
                                               unsigned short* __restrict__ C,
                                               int K, int lda, int ncols) {
  int i  = blockIdx.x * 256 + threadIdx.x;
  int j0 = blockIdx.y * 8;
  float acc[8] = {0.f,0.f,0.f,0.f,0.f,0.f,0.f,0.f};
  for (int k = 0; k < K; ++k) {
    float wb = Bm[(long)k * ncols + i];
#pragma unroll
    for (int r = 0; r < 8; ++r) acc[r] += A[(long)(j0 + r) * lda + k] * wb;
  }
#pragma unroll
  for (int r = 0; r < 8; ++r) C[(long)(j0 + r) * ncols + i] = f2b(acc[r]);
}

// ---------------- fused biases ----------------
__global__ void k_bfuse(const float* __restrict__ ipw, const float* __restrict__ ipb,
                        const float* __restrict__ bx, const float* __restrict__ by,
                        float* __restrict__ bqx, float* __restrict__ bkv) {
  int o    = blockIdx.x * 4 + (threadIdx.x >> 6);   // 0..2303 (grid 576)
  int lane = threadIdx.x & 63;
  int sec  = o / 768, jj = o - sec * 768;
  const float* Arow = ipw + (long)o * 768;
  const float* vb   = (sec == 0) ? bx : by;
  float s = 0.f;
  for (int k = lane; k < 768; k += 64) s += Arow[k] * vb[k];
#pragma unroll
  for (int d = 32; d > 0; d >>= 1) s += __shfl_down(s, d);
  if (lane == 0) {
    s += ipb[o];
    if (sec == 0) bqx[jj] = s;
    else if (sec == 1) bkv[jj] = s;
    else bkv[768 + jj] = s;
  }
}

// ---------------- prompt queries ----------------
__global__ void k_qprompt(const float* __restrict__ ipw, const float* __restrict__ ipb,
                          const float* __restrict__ prompt, unsigned short* __restrict__ qpf) {
  int o    = blockIdx.x * 4 + (threadIdx.x >> 6);   // 0..3071 (grid 768)
  int lane = threadIdx.x & 63;
  int p = o / 768, j = o - p * 768;
  const float* Wqr = ipw + (long)j * 768;
  const float* pr  = prompt + (long)p * 768;
  float s = 0.f;
  for (int k = lane; k < 768; k += 64) s += Wqr[k] * pr[k];
#pragma unroll
  for (int d = 32; d > 0; d >>= 1) s += __shfl_down(s, d);
  if (lane == 0) qpf[o] = f2b(s + ipb[j]);
}

// ---------------- 128² GEMM (proven m97 structure) — used for q_x ----------------
template <typename OutT>
__global__ __launch_bounds__(256) void k_gemm(const unsigned short* __restrict__ A,
                                              const unsigned short* __restrict__ Bw,
                                              const float* __restrict__ bias,
                                              OutT* __restrict__ C,
                                              int M, int Nn, int K, int nbx) {
  const int tid  = threadIdx.x;
  const int lane = tid & 63, wid = tid >> 6;
  const int wm = wid >> 1, wn = wid & 1;
  const int lr = lane & 15, lk = lane >> 4;

  const int nwg = gridDim.x, orig = blockIdx.x;
  const int q8 = nwg >> 3, r8 = nwg & 7, xc = orig & 7;
  const int wg = (xc < r8 ? xc * (q8 + 1) : r8 * (q8 + 1) + (xc - r8) * q8) + (orig >> 3);
  const int bn = wg % nbx, bm = wg / nbx;
  const int m0 = bm * 128, n0 = bn * 128;

  __shared__ __attribute__((aligned(16))) unsigned short As[2][128 * 32];
  __shared__ __attribute__((aligned(16))) unsigned short Bs[2][128 * 32];

  f32x4 acc[4][4];
#pragma unroll
  for (int nt = 0; nt < 4; ++nt) {
    float bv = bias[n0 + wn * 64 + nt * 16 + lr];
    f32x4 bvv = {bv, bv, bv, bv};
#pragma unroll
    for (int mt = 0; mt < 4; ++mt) acc[mt][nt] = bvv;
  }

  const int NS = K >> 5;
  const int crow = lane >> 2, ck8 = (lane & 3) * 8;

  auto stage = [&](int buf, int ks) {
#pragma unroll
    for (int i = 0; i < 2; ++i) {
      int c = wid * 2 + i;
      int row = c * 16 + crow;
      GLDS(&A[(long)(m0 + row) * K + ks * 32 + ck8], &As[buf][c * 512]);
      GLDS(&Bw[(long)(n0 + row) * K + ks * 32 + ck8], &Bs[buf][c * 512]);
    }
  };

  stage(0, 0);
  __syncthreads();

  for (int t = 0; t < NS; ++t) {
    const int cur = t & 1, nb = cur ^ 1;
    if (t + 1 < NS) stage(nb, t + 1);
    bf16x8 af[4], bfr[4];
#pragma unroll
    for (int mt = 0; mt < 4; ++mt)
      af[mt] = *(const bf16x8*)&As[cur][(wm * 64 + mt * 16 + lr) * 32 + lk * 8];
#pragma unroll
    for (int nt = 0; nt < 4; ++nt)
      bfr[nt] = *(const bf16x8*)&Bs[cur][(wn * 64 + nt * 16 + lr) * 32 + lk * 8];
#pragma unroll
    for (int mt = 0; mt < 4; ++mt)
#pragma unroll
      for (int nt = 0; nt < 4; ++nt)
        acc[mt][nt] = __builtin_amdgcn_mfma_f32_16x16x32_bf16(af[mt], bfr[nt], acc[mt][nt], 0, 0, 0);
    __syncthreads();
  }

#pragma unroll
  for (int mt = 0; mt < 4; ++mt)
#pragma unroll
    for (int nt = 0; nt < 4; ++nt) {
      int col = n0 + wn * 64 + nt * 16 + lr;
#pragma unroll
      for (int r = 0; r < 4; ++r) {
        int row = m0 + wm * 64 + mt * 16 + lk * 4 + r;
        float v = acc[mt][nt][r];
        if constexpr (sizeof(OutT) == 4) C[(long)row * Nn + col] = v;
        else                             C[(long)row * Nn + col] = f2b(v);
      }
    }
}

// ---------------- 256² 8-phase GEMM (T2+T3+T4+T5) ----------------
// 512 thr = 8 waves (2M x 4N), BM=BN=256, BK=64, per-wave C = 128x64.
// LDS 128 KiB: [buf][half][128x64] for A and B, st_16x32 XOR swizzle
// (linear global_load_lds dest + inverse-swizzled global src + swizzled ds_read).
// 4 phases per K-tile; counted vmcnt(2) once per K-tile, placed BEFORE the
// iteration's closing barrier (cross-wave publish), never 0 in steady state.
template <typename OutT>
__global__ __launch_bounds__(512, 2) void k_gemm8(const unsigned short* __restrict__ A,
                                                  const unsigned short* __restrict__ Bw,
                                                  const float* __restrict__ bias,
                                                  OutT* __restrict__ C,
                                                  int M, int Nn, int K, int nbx) {
  const int tid  = threadIdx.x;
  const int lane = tid & 63, wid = tid >> 6;
  const int wm = wid >> 2, wn = wid & 3;          // 2 x 4 waves
  const int lr = lane & 15, lk = lane >> 4;

  const int nwg = gridDim.x, orig = blockIdx.x;
  const int q8 = nwg >> 3, r8 = nwg & 7, xc = orig & 7;
  const int wg = (xc < r8 ? xc * (q8 + 1) : r8 * (q8 + 1) + (xc - r8) * q8) + (orig >> 3);
  const int bn = wg % nbx, bm = wg / nbx;
  const long m0 = (long)bm * 256, n0 = (long)bn * 256;

  __shared__ __attribute__((aligned(16))) unsigned short As[2][2][8192];  // [buf][half][128*64]
  __shared__ __attribute__((aligned(16))) unsigned short Bs[2][2][8192];

  f32x4 acc[8][4];
#pragma unroll
  for (int nt = 0; nt < 4; ++nt) {
    float bv = bias[n0 + wn * 64 + nt * 16 + lr];
    f32x4 bvv = {bv, bv, bv, bv};
#pragma unroll
    for (int mt = 0; mt < 8; ++mt) acc[mt][nt] = bvv;
  }

  const int NT = K >> 6;            // K-tiles of 64

  // stage one half-tile (128 rows x 64 k) : 2 x global_load_lds per thread.
  // dest linear; source column pre-swizzled so LDS holds the st_16x32 image.
  auto stage = [&](int buf, int kt, int isB, int h) {
#pragma unroll
    for (int j = 0; j < 2; ++j) {
      int c   = j * 8 + wid;                         // 1KB chunk 0..15 (wave-uniform)
      int row = c * 8 + (lane >> 3);                 // 0..127
      int col = ((lane & 7) * 8) ^ ((row & 7) << 3); // elems, inverse-swizzled
      const unsigned short* g = isB
          ? &Bw[(n0 + h * 128 + row) * (long)K + kt * 64 + col]
          : &A [(m0 + h * 128 + row) * (long)K + kt * 64 + col];
      unsigned short* l = isB ? &Bs[buf][h][c * 512] : &As[buf][h][c * 512];
      GLDS(g, l);
    }
  };
  // swizzled ds_read of one 16x32 MFMA A/B fragment
  auto ldsA = [&](int buf, int mt, int kk) -> bf16x8 {
    int r = mt * 16 + lr;
    int off = r * 128 + ((kk * 64 + lk * 16) ^ ((lr & 7) << 4));   // bytes
    return *(const bf16x8*)((const char*)&As[buf][wm][0] + off);
  };
  auto ldsB = [&](int buf, int nt, int kk) -> bf16x8 {
    int r = (wn & 1) * 64 + nt * 16 + lr;
    int off = r * 128 + ((kk * 64 + lk * 16) ^ ((lr & 7) << 4));
    return *(const bf16x8*)((const char*)&Bs[buf][wn >> 1][0] + off);
  };

  // ---- prologue: tile0 (all 4 halves) + tile1 A-half0 ----
  stage(0, 0, 0, 0); stage(0, 0, 0, 1); stage(0, 0, 1, 0); stage(0, 0, 1, 1);
  if (NT > 1) {
    stage(1, 1, 0, 0);
    asm volatile("s_waitcnt vmcnt(2)" ::: "memory");
  } else {
    asm volatile("s_waitcnt vmcnt(0)" ::: "memory");
  }
  __builtin_amdgcn_s_barrier();

  for (int u = 0; u < NT; ++u) {
    const int cb = u & 1;
    bf16x8 a[4][2], b0[2][2], b1[2][2];

    // ---- P1: read A(mt0-3)+B(nt0-1); stage A1(u+1); MFMA quad (0-3)x(0-1) ----
#pragma unroll
    for (int mt = 0; mt < 4; ++mt) { a[mt][0] = ldsA(cb, mt, 0); a[mt][1] = ldsA(cb, mt, 1); }
#pragma unroll
    for (int nt = 0; nt < 2; ++nt) { b0[nt][0] = ldsB(cb, nt, 0); b0[nt][1] = ldsB(cb, nt, 1); }
    if (u + 1 < NT) stage(cb ^ 1, u + 1, 0, 1);
    __builtin_amdgcn_s_barrier();
    asm volatile("s_waitcnt lgkmcnt(0)" ::: "memory");
    __builtin_amdgcn_s_setprio(1);
#pragma unroll
    for (int mt = 0; mt < 4; ++mt)
#pragma unroll
      for (int nt = 0; nt < 2; ++nt)
#pragma unroll
        for (int kk = 0; kk < 2; ++kk)
          acc[mt][nt] = __builtin_amdgcn_mfma_f32_16x16x32_bf16(a[mt][kk], b0[nt][kk], acc[mt][nt], 0, 0, 0);
    __builtin_amdgcn_s_setprio(0);
    __builtin_amdgcn_s_barrier();

    // ---- P2: read B(nt2-3); stage B0(u+1); MFMA quad (0-3)x(2-3) ----
#pragma unroll
    for (int nt = 0; nt < 2; ++nt) { b1[nt][0] = ldsB(cb, 2 + nt, 0); b1[nt][1] = ldsB(cb, 2 + nt, 1); }
    if (u + 1 < NT) stage(cb ^ 1, u + 1, 1, 0);
    __builtin_amdgcn_s_barrier();
    asm volatile("s_waitcnt lgkmcnt(0)" ::: "memory");
    __builtin_amdgcn_s_setprio(1);
#pragma unroll
    for (int mt = 0; mt < 4; ++mt)
#pragma unroll
      for (int nt = 0; nt < 2; ++nt)
#pragma unroll
        for (int kk = 0; kk < 2; ++kk)
          acc[mt][2 + nt] = __builtin_amdgcn_mfma_f32_16x16x32_bf16(a[mt][kk], b1[nt][kk], acc[mt][2 + nt], 0, 0, 0);
    __builtin_amdgcn_s_setprio(0);
    __builtin_amdgcn_s_barrier();

    // ---- P3: read A(mt4-7); stage B1(u+1); MFMA quad (4-7)x(2-3) ----
#pragma unroll
    for (int mt = 0; mt < 4; ++mt) { a[mt][0] = ldsA(cb, 4 + mt, 0); a[mt][1] = ldsA(cb, 4 + mt, 1); }
    if (u + 1 < NT) stage(cb ^ 1, u + 1, 1, 1);
    __builtin_amdgcn_s_barrier();
    asm volatile("s_waitcnt lgkmcnt(0)" ::: "memory");
    __builtin_amdgcn_s_setprio(1);
#pragma unroll
    for (int mt = 0; mt < 4; ++mt)
#pragma unroll
      for (int nt = 0; nt < 2; ++nt)
#pragma unroll
        for (int kk = 0; kk < 2; ++kk)
          acc[4 + mt][2 + nt] = __builtin_amdgcn_mfma_f32_16x16x32_bf16(a[mt][kk], b1[nt][kk], acc[4 + mt][2 + nt], 0, 0, 0);
    __builtin_amdgcn_s_setprio(0);
    __builtin_amdgcn_s_barrier();

    // ---- P4: stage A0(u+2) into freed active-buf region; MFMA quad (4-7)x(0-1) ----
    if (u + 2 < NT) stage(cb, u + 2, 0, 0);
    __builtin_amdgcn_s_barrier();
    __builtin_amdgcn_s_setprio(1);
#pragma unroll
    for (int mt = 0; mt < 4; ++mt)
#pragma unroll
      for (int nt = 0; nt < 2; ++nt)
#pragma unroll
        for (int kk = 0; kk < 2; ++kk)
          acc[4 + mt][nt] = __builtin_amdgcn_mfma_f32_16x16x32_bf16(a[mt][kk], b0[nt][kk], acc[4 + mt][nt], 0, 0, 0);
    __builtin_amdgcn_s_setprio(0);

    // counted drain BEFORE the closing barrier: after the barrier, every
    // wave's tile-(u+1) loads are known-landed by ALL waves (fix for r4 race).
    if (u + 2 < NT)       asm volatile("s_waitcnt vmcnt(2)" ::: "memory");
    else if (u + 1 < NT)  asm volatile("s_waitcnt vmcnt(0)" ::: "memory");
    __builtin_amdgcn_s_barrier();
  }

  // ---- epilogue ----
#pragma unroll
  for (int mt = 0; mt < 8; ++mt)
#pragma unroll
    for (int nt = 0; nt < 4; ++nt) {
      long col = n0 + wn * 64 + nt * 16 + lr;
#pragma unroll
      for (int r = 0; r < 4; ++r) {
        long row = m0 + wm * 128 + mt * 16 + lk * 4 + r;
        float v = acc[mt][nt][r];
        if constexpr (sizeof(OutT) == 4) C[row * Nn + col] = v;
        else                             C[row * Nn + col] = f2b(v);
      }
    }
}

// ---------------- attention, coalesced ----------------
__global__ __launch_bounds__(512) void k_attn(const unsigned short* __restrict__ kv,
                                              const unsigned short* __restrict__ qx,
                                              const unsigned short* __restrict__ qp,
                                              unsigned short* __restrict__ o) {
  __shared__ unsigned short Ks[32 * 772];
  __shared__ unsigned short Qs[6 * 768];
  __shared__ float Ss[120 * 16];
  const int tid = threadIdx.x;
  const long p0 = (long)blockIdx.x * 2;

  for (int i = tid; i < 32 * 96; i += 512) {
    int r = i / 96, c8 = i - (i / 96) * 96;
    u16x8 vv = *(const u16x8*)&kv[((p0 + (r >> 4)) * 16 + (r & 15)) * 1536 + c8 * 8];
    *(u16x8*)&Ks[r * 772 + c8 * 8] = vv;
  }
  for (int i = tid; i < 6 * 96; i += 512) {
    int r = i / 96, c8 = i - (i / 96) * 96;
    const unsigned short* src = (r < 2) ? &qx[(p0 + r) * 768 + c8 * 8]
                                        : &qp[(long)(r - 2) * 768 + c8 * 8];
    *(u16x8*)&Qs[r * 768 + c8 * 8] = *(const u16x8*)src;
  }
  __syncthreads();

  for (int idx = tid; idx < 1920; idx += 512) {
    int w = idx & 15, rest = idx >> 4;
    int h = rest % 12, pq = rest / 12;
    int q5 = pq % 5, p = pq / 5;
    const unsigned short* krow = &Ks[(p * 16 + w) * 772 + h * 64];
    const unsigned short* qrow = &Qs[((q5 == 0) ? p : 1 + q5) * 768 + h * 64];
    float s = 0.f;
#pragma unroll
    for (int j = 0; j < 8; ++j) {
      u16x8 kk = *(const u16x8*)&krow[j * 8];
      u16x8 qq = *(const u16x8*)&qrow[j * 8];
#pragma unroll
      for (int e = 0; e < 8; ++e) s += bf2f(qq[e]) * bf2f(kk[e]);
    }
    s *= 0.125f;
    float m = s;
#pragma unroll
    for (int d = 1; d < 16; d <<= 1) m = fmaxf(m, __shfl_xor(m, d));
    float e = __expf(s - m);
    float sum = e;
#pragma unroll
    for (int d = 1; d < 16; d <<= 1) sum += __shfl_xor(sum, d);
    Ss[rest * 16 + w] = e / sum;
  }
  __syncthreads();

  for (int idx = tid; idx < 960; idx += 512) {
    int d8 = idx % 96, pq = idx / 96;
    int q5 = pq % 5, p = pq / 5, h = d8 >> 3;
    const float* arow = &Ss[(pq * 12 + h) * 16];
    const unsigned short* vbase = &kv[(p0 + p) * 16 * 1536 + 768 + d8 * 8];
    float acc[8] = {0.f,0.f,0.f,0.f,0.f,0.f,0.f,0.f};
#pragma unroll
    for (int w = 0; w < 16; ++w) {
      u16x8 vv = *(const u16x8*)&vbase[(long)w * 1536];
      float aw = arow[w];
#pragma unroll
      for (int e = 0; e < 8; ++e) acc[e] += aw * bf2f(vv[e]);
    }
    u16x8 ov;
#pragma unroll
    for (int e = 0; e < 8; ++e) ov[e] = f2b(acc[e]);
    *(u16x8*)&o[((p0 + p) * 5 + q5) * 768 + d8 * 8] = ov;
  }
}

// ---------------------------------------------------------------------------
extern "C" void kernel_launch(void* const* d_in, const int* in_sizes, int n_in,
                              void* d_out, int out_size, void* d_ws, size_t ws_size,
                              hipStream_t stream) {
  const float* x      = (const float*)d_in[0];   // [32,576,1536]
  const float* y      = (const float*)d_in[1];   // [32,9216,1024]
  const float* Wx     = (const float*)d_in[2];   // [768,1536]
  const float* bx     = (const float*)d_in[3];   // [768]
  const float* Wy     = (const float*)d_in[4];   // [768,1024]
  const float* by     = (const float*)d_in[5];   // [768]
  const float* prompt = (const float*)d_in[6];   // [1,4,768]
  const float* ipw    = (const float*)d_in[7];   // [2304,768]
  const float* ipb    = (const float*)d_in[8];   // [2304]
  const float* outw   = (const float*)d_in[9];   // [768,768]
  const float* outb   = (const float*)d_in[10];  // [768]
  float* out = (float*)d_out;

  char* ws = (char*)d_ws;
  size_t off = 0;
  auto alloc = [&](size_t bytes) -> void* {
    void* p = ws + off; off += (bytes + 255) & ~(size_t)255; return p;
  };
  unsigned short* kvb  = (unsigned short*)alloc(294912UL * 1536 * 2);  // 906 MB
  unsigned short* qxb  = (unsigned short*)alloc(18432UL * 768 * 2);    // 28 MB
  unsigned short* ob   = (unsigned short*)alloc(92160UL * 768 * 2);    // 142 MB
  unsigned short* Wqx  = (unsigned short*)alloc(768UL * 1536 * 2);
  unsigned short* Wkv  = (unsigned short*)alloc(1536UL * 1024 * 2);
  unsigned short* oww  = (unsigned short*)alloc(768UL * 768 * 2);
  unsigned short* qpf  = (unsigned short*)alloc(4UL * 768 * 2);
  float*          bqx  = (float*)alloc(768 * 4);
  float*          bkv  = (float*)alloc(1536 * 4);
  unsigned short* xb   = ob;  // alias (dead before k_attn writes ob)
  unsigned short* ybc  = (unsigned short*)(ws + off);
  long rpc = (long)((ws_size - off) / (1024 * 2)) & ~255L;  // rows/chunk, mult of 256
  if (rpc > 294912) rpc = 294912;
  if (rpc < 256) rpc = 256;

  // ---- weight prep ----
  k_cvt<<<dim3(288), dim3(256), 0, stream>>>(outw, oww, 768L * 768 / 8);
  k_wfuse<<<dim3(6, 96), dim3(256), 0, stream>>>(ipw,              Wx, Wqx,              768, 768, 1536);
  k_wfuse<<<dim3(4, 96), dim3(256), 0, stream>>>(ipw + 768 * 768,  Wy, Wkv,              768, 768, 1024);
  k_wfuse<<<dim3(4, 96), dim3(256), 0, stream>>>(ipw + 1536 * 768, Wy, Wkv + 768 * 1024, 768, 768, 1024);
  k_bfuse<<<dim3(576), dim3(256), 0, stream>>>(ipw, ipb, bx, by, bqx, bkv);
  k_qprompt<<<dim3(768), dim3(256), 0, stream>>>(ipw, ipb, prompt, qpf);

  // ---- x -> bf16; q_x = xb @ Wqx^T + bqx  (M=18432, N=768, K=1536) ----
  k_cvt<<<dim3(2048), dim3(256), 0, stream>>>(x, xb, 18432L * 1536 / 8);
  k_gemm<unsigned short><<<dim3(144 * 6), dim3(256), 0, stream>>>(
      xb, Wqx, bqx, qxb, 18432, 768, 1536, 6);

  // ---- kv = bf16(y) @ Wkv^T + bkv  (M=294912, N=1536, K=1024), 8-phase ----
  long row0 = 0;
  while (row0 < 294912) {
    long mc = 294912 - row0 < rpc ? 294912 - row0 : rpc;
    k_cvt<<<dim3(2048), dim3(256), 0, stream>>>(y + row0 * 1024, ybc, mc * 128);
    k_gemm8<unsigned short><<<dim3((int)(mc / 256) * 6), dim3(512), 0, stream>>>(
        ybc, Wkv, bkv, kvb + row0 * 1536, (int)mc, 1536, 1024, 6);
    row0 += mc;
  }

  // ---- attention -> o bf16 ----
  k_attn<<<dim3(9216), dim3(512), 0, stream>>>(kvb, qxb, qpf, ob);

  // ---- out = o @ oww^T + outb  (M=92160, N=768, K=768) -> f32, 8-phase ----
  k_gemm8<float><<<dim3(360 * 3), dim3(512), 0, stream>>>(
      ob, oww, outb, out, 92160, 768, 768, 3);
}